// Round 4
// baseline (202.870 us; speedup 1.0000x reference)
//
#include <hip/hip_runtime.h>

#define C 192
#define H 56
#define W 56
#define HW (H * W)
#define CHW (C * HW)
#define NB 32
#define PPS 36
#define EPSLN 1e-5f

// ---- DPP cross-lane helpers (16-lane rows == our sub-groups) ----
#define CTL_SHL1 0x101
#define CTL_SHL2 0x102
#define CTL_SHR1 0x111
#define CTL_SHR2 0x112

template<int CTRL>
__device__ __forceinline__ float dppf(float v) {
    return __int_as_float(__builtin_amdgcn_update_dpp(
        0, __float_as_int(v), CTRL, 0xf, 0xf, true));
}

struct __attribute__((aligned(16))) f4 { float x, y, z, w; };
struct __attribute__((aligned(8))) us4 { unsigned short x, y, z, w; };

__device__ __forceinline__ unsigned short f2bf(float v) {
    return (unsigned short)((__float_as_uint(v) + 0x8000u) >> 16);
}
__device__ __forceinline__ float bf2f(unsigned short u) {
    return __uint_as_float(((unsigned int)u) << 16);
}

__device__ __forceinline__ f4 f4z() { return {0.f, 0.f, 0.f, 0.f}; }
__device__ __forceinline__ f4 f4b(float s) { return {s, s, s, s}; }
__device__ __forceinline__ f4 fma4(f4 a, float s, f4 c) {
    return { fmaf(a.x, s, c.x), fmaf(a.y, s, c.y),
             fmaf(a.z, s, c.z), fmaf(a.w, s, c.w) };
}
// lane l holds w in [4l, 4l+4); shifted view: comp k = row[4l+k+s]
__device__ __forceinline__ f4 shp1(f4 v){ return { v.y, v.z, v.w, dppf<CTL_SHL1>(v.x) }; }
__device__ __forceinline__ f4 shm1(f4 v){ return { dppf<CTL_SHR1>(v.w), v.x, v.y, v.z }; }
__device__ __forceinline__ f4 shp3(f4 v){ return { v.w, dppf<CTL_SHL1>(v.x),
                                                   dppf<CTL_SHL1>(v.y), dppf<CTL_SHL1>(v.z) }; }
__device__ __forceinline__ f4 shm3(f4 v){ return { dppf<CTL_SHR1>(v.y), dppf<CTL_SHR1>(v.z),
                                                   dppf<CTL_SHR1>(v.w), v.x }; }
__device__ __forceinline__ f4 shp5(f4 v){ return { dppf<CTL_SHL1>(v.y), dppf<CTL_SHL1>(v.z),
                                                   dppf<CTL_SHL1>(v.w), dppf<CTL_SHL2>(v.x) }; }
__device__ __forceinline__ f4 shm5(f4 v){ return { dppf<CTL_SHR2>(v.w), dppf<CTL_SHR1>(v.x),
                                                   dppf<CTL_SHR1>(v.y), dppf<CTL_SHR1>(v.z) }; }

__device__ __forceinline__ f4 prelu_acc(f4 acc, f4 y, float a) {
    acc.x += fmaxf(y.x, 0.f) + a * fminf(y.x, 0.f);
    acc.y += fmaxf(y.y, 0.f) + a * fminf(y.y, 0.f);
    acc.z += fmaxf(y.z, 0.f) + a * fminf(y.z, 0.f);
    acc.w += fmaxf(y.w, 0.f) + a * fminf(y.w, 0.f);
    return acc;
}

// ---- prep: fold params into packed 36-float records (d_ws) ----
__global__ void prep_kernel(const float* __restrict__ bias,
                            const float* __restrict__ conv_w,
                            const float* __restrict__ conv_b,
                            const float* __restrict__ move1,
                            const float* __restrict__ alpha,
                            const float* __restrict__ move2,
                            const float* __restrict__ ln_g,
                            const float* __restrict__ ln_b,
                            float* __restrict__ pp, float* __restrict__ gb) {
    const int c = threadIdx.x;
    if (c >= C) return;
    float* pc = pp + c * PPS;
    #pragma unroll
    for (int i = 0; i < 3; ++i)
        #pragma unroll
        for (int k = 0; k < 9; ++k)
            pc[i * 9 + k] = conv_w[(size_t)(i * C + c) * 9 + k];
    #pragma unroll
    for (int i = 0; i < 3; ++i) {
        pc[27 + i] = conv_b[i * C + c] - move1[i * C + c];
        pc[30 + i] = alpha[i * C + c];
    }
    pc[33] = bias[c];
    pc[34] = move2[0 * C + c] + move2[1 * C + c] + move2[2 * C + c];
    pc[35] = 0.f;
    gb[2 * c]     = ln_g[c];
    gb[2 * c + 1] = ln_b[c];
}

__global__ __launch_bounds__(256, 4) void msgdc_kernel(
    const float* __restrict__ x, const float* __restrict__ pp,
    const float* __restrict__ gb, float* __restrict__ out)
{
    __shared__ unsigned short tile[C * W];   // 21.5 KB bf16 pre-LN
    __shared__ float sred[4][16][8];         // 2 KB cross-wave LN partials

    const int t = threadIdx.x;
    const int lane = t & 63;
    const int wv = __builtin_amdgcn_readfirstlane(t >> 6);
    const int l = lane & 15;             // position within 16-lane sub-group
    const bool act = (l < 14);           // 14 lanes x float4 = 56 pixels
    const float act_f = act ? 1.f : 0.f;
    const int lw = act ? 4 * l : 52;     // clamped (safe) w offset for idle lanes

    const int blk = blockIdx.x;
    const int gid = (blk & 7) * 224 + (blk >> 3);   // XCD-contiguous (b,h)
    const int b = gid / H;
    const int h = gid - b * H;

    // uniform row validity, offsets {-5,-3,-1,0,+1,+3,+5}
    const bool vr[7] = { h >= 5, h >= 3, h >= 1, true,
                         h <= H - 2, h <= H - 4, h <= H - 6 };
    const int  ro[7] = { -5 * W, -3 * W, -1 * W, 0, 1 * W, 3 * W, 5 * W };
    float vm[7];
    #pragma unroll
    for (int k = 0; k < 7; ++k) vm[k] = vr[k] ? 1.f : 0.f;

    const int cbase = wv * 48 + (lane >> 4);
    const float* xc0 = x + (size_t)b * CHW + (size_t)cbase * HW + h * W + lw;

    f4 s4 = f4z(), q4 = f4z();

    #pragma unroll 1
    for (int j = 0; j < 12; ++j) {
        const int c = cbase + 4 * j;

        // rows (no register double-buffer: rely on 4 waves/SIMD TLP)
        const float* xc = xc0 + (size_t)(4 * j) * HW;
        f4 r[7];
        #pragma unroll
        for (int k = 0; k < 7; ++k)
            r[k] = vr[k] ? *(const f4*)(xc + ro[k]) : f4z();

        // packed folded params (group-uniform address, L2-hot)
        const float* pc = pp + c * PPS;
        float wf[36];
        #pragma unroll
        for (int k = 0; k < 9; ++k)
            *(f4*)(wf + 4 * k) = *(const f4*)(pc + 4 * k);

        const float bs = wf[33];
        // bias on valid in-image samples only; idle lanes forced to 0
        #pragma unroll
        for (int k = 0; k < 7; ++k) {
            const float bk = bs * vm[k] * act_f;
            r[k].x = fmaf(r[k].x, act_f, bk);
            r[k].y = fmaf(r[k].y, act_f, bk);
            r[k].z = fmaf(r[k].z, act_f, bk);
            r[k].w = fmaf(r[k].w, act_f, bk);
        }

        f4 acc = f4b(wf[34]);   // m2 fold
        {   // d = 1: rows r[2],r[3],r[4], weights wf[0..8]
            f4 y = f4b(wf[27]);
            y = fma4(shm1(r[2]), wf[0], y);
            y = fma4(r[2],       wf[1], y);
            y = fma4(shp1(r[2]), wf[2], y);
            y = fma4(shm1(r[3]), wf[3], y);
            y = fma4(r[3],       wf[4], y);
            y = fma4(shp1(r[3]), wf[5], y);
            y = fma4(shm1(r[4]), wf[6], y);
            y = fma4(r[4],       wf[7], y);
            y = fma4(shp1(r[4]), wf[8], y);
            acc = prelu_acc(acc, y, wf[30]);
        }
        {   // d = 3: rows r[1],r[3],r[5], weights wf[9..17]
            f4 y = f4b(wf[28]);
            y = fma4(shm3(r[1]), wf[9],  y);
            y = fma4(r[1],       wf[10], y);
            y = fma4(shp3(r[1]), wf[11], y);
            y = fma4(shm3(r[3]), wf[12], y);
            y = fma4(r[3],       wf[13], y);
            y = fma4(shp3(r[3]), wf[14], y);
            y = fma4(shm3(r[5]), wf[15], y);
            y = fma4(r[5],       wf[16], y);
            y = fma4(shp3(r[5]), wf[17], y);
            acc = prelu_acc(acc, y, wf[31]);
        }
        {   // d = 5: rows r[0],r[3],r[6], weights wf[18..26]
            f4 y = f4b(wf[29]);
            y = fma4(shm5(r[0]), wf[18], y);
            y = fma4(r[0],       wf[19], y);
            y = fma4(shp5(r[0]), wf[20], y);
            y = fma4(shm5(r[3]), wf[21], y);
            y = fma4(r[3],       wf[22], y);
            y = fma4(shp5(r[3]), wf[23], y);
            y = fma4(shm5(r[6]), wf[24], y);
            y = fma4(r[6],       wf[25], y);
            y = fma4(shp5(r[6]), wf[26], y);
            acc = prelu_acc(acc, y, wf[32]);
        }

        s4.x += acc.x; s4.y += acc.y; s4.z += acc.z; s4.w += acc.w;
        q4.x = fmaf(acc.x, acc.x, q4.x); q4.y = fmaf(acc.y, acc.y, q4.y);
        q4.z = fmaf(acc.z, acc.z, q4.z); q4.w = fmaf(acc.w, acc.w, q4.w);

        if (act) {
            us4 p = { f2bf(acc.x), f2bf(acc.y), f2bf(acc.z), f2bf(acc.w) };
            *(us4*)(tile + c * W + lw) = p;   // own-lane stash
        }
    }

    // ---- LN reduction: xor16/32 within wave, then cross-wave via LDS ----
    #pragma unroll
    for (int m = 16; m <= 32; m <<= 1) {
        s4.x += __shfl_xor(s4.x, m, 64); s4.y += __shfl_xor(s4.y, m, 64);
        s4.z += __shfl_xor(s4.z, m, 64); s4.w += __shfl_xor(s4.w, m, 64);
        q4.x += __shfl_xor(q4.x, m, 64); q4.y += __shfl_xor(q4.y, m, 64);
        q4.z += __shfl_xor(q4.z, m, 64); q4.w += __shfl_xor(q4.w, m, 64);
    }
    if (lane < 14) {
        *(f4*)&sred[wv][lane][0] = s4;
        *(f4*)&sred[wv][lane][4] = q4;
    }
    __syncthreads();

    f4 S = f4z(), Q = f4z();
    #pragma unroll
    for (int w2 = 0; w2 < 4; ++w2) {
        const f4 a = *(const f4*)&sred[w2][l][0];
        const f4 bq = *(const f4*)&sred[w2][l][4];
        S.x += a.x; S.y += a.y; S.z += a.z; S.w += a.w;
        Q.x += bq.x; Q.y += bq.y; Q.z += bq.z; Q.w += bq.w;
    }
    const float inv = 1.f / (float)C;
    f4 mean = { S.x * inv, S.y * inv, S.z * inv, S.w * inv };
    f4 rstd = { rsqrtf(Q.x * inv - mean.x * mean.x + EPSLN),
                rsqrtf(Q.y * inv - mean.y * mean.y + EPSLN),
                rsqrtf(Q.z * inv - mean.z * mean.z + EPSLN),
                rsqrtf(Q.w * inv - mean.w * mean.w + EPSLN) };

    float* ob = out + (size_t)b * CHW + (size_t)cbase * HW + h * W + lw;
    #pragma unroll 2
    for (int j = 0; j < 12; ++j) {
        const int c = cbase + 4 * j;
        const float ga = gb[2 * c], be = gb[2 * c + 1];
        if (act) {
            const us4 p = *(const us4*)(tile + c * W + lw);
            f4 o;
            o.x = fmaf((bf2f(p.x) - mean.x) * rstd.x, ga, be);
            o.y = fmaf((bf2f(p.y) - mean.y) * rstd.y, ga, be);
            o.z = fmaf((bf2f(p.z) - mean.z) * rstd.z, ga, be);
            o.w = fmaf((bf2f(p.w) - mean.w) * rstd.w, ga, be);
            *(f4*)(ob + (size_t)(4 * j) * HW) = o;
        }
    }
}

extern "C" void kernel_launch(void* const* d_in, const int* in_sizes, int n_in,
                              void* d_out, int out_size, void* d_ws, size_t ws_size,
                              hipStream_t stream) {
    const float* x       = (const float*)d_in[0];
    const float* bias    = (const float*)d_in[1];
    const float* conv_w  = (const float*)d_in[2];
    const float* conv_b  = (const float*)d_in[3];
    const float* move1   = (const float*)d_in[4];
    const float* alpha   = (const float*)d_in[5];
    const float* move2   = (const float*)d_in[6];
    const float* ln_g    = (const float*)d_in[7];
    const float* ln_b    = (const float*)d_in[8];
    float* out = (float*)d_out;

    float* pp = (float*)d_ws;                 // 192*36 floats
    float* gbp = pp + C * PPS;                // 192*2 floats

    prep_kernel<<<1, 256, 0, stream>>>(bias, conv_w, conv_b, move1, alpha,
                                       move2, ln_g, ln_b, pp, gbp);
    msgdc_kernel<<<NB * H, 256, 0, stream>>>(x, pp, gbp, out);
}